// Round 2
// baseline (1485.167 us; speedup 1.0000x reference)
//
#include <hip/hip_runtime.h>
#include <stdint.h>

#define R_NODES 256
#define M_SAMP  512
#define S_STEPS 512
#define OUT_N   10

// ---------------- layout detection for bool inputs ----------------
// If bools were uploaded as int32, byte (4f+1) of every element is 0.
// If uploaded as uint8, ~half those bytes are 1.  flag=1 => uint8 layout.
__global__ void detect_layout(const uint8_t* __restrict__ x, int* __restrict__ flag) {
    __shared__ int any;
    if (threadIdx.x == 0) any = 0;
    __syncthreads();
    int acc = 0;
    for (int i = 0; i < 64; ++i)
        acc |= x[(size_t)(threadIdx.x * 64 + i) * 4 + 1];
    if (acc) atomicOr(&any, 1);
    __syncthreads();
    if (threadIdx.x == 0) *flag = any ? 1 : 0;
}

// ---------------- pack x bits: one uint32 per (m,s) ----------------
__global__ void pack_x(const uint8_t* __restrict__ x, const int* __restrict__ flag,
                       uint32_t* __restrict__ xp) {
    const int stride = (*flag) ? 1 : 4;
    const int f = blockIdx.x * blockDim.x + threadIdx.x;      // element idx, M*S*32 total
    const int val = x[(size_t)f * stride];
    const uint64_t mask = __ballot(val != 0);
    const int lane = threadIdx.x & 63;
    if ((lane & 31) == 0) {
        uint32_t w = (lane & 32) ? (uint32_t)(mask >> 32) : (uint32_t)mask;
        xp[f >> 5] = w;
    }
}

// ---------------- build byte-chunk partial-sum table (permuted bits) ----
// T2[(v*32 + c)*256 + j]: bit p of v refers to node column
//     k = c*8 + (p&1)*4 + (p>>1)
// matching the main kernel's ballot-derived byte
//     u_c = ((b0>>2c)&3) | ((b1>>2c)&3)<<2 | ((b2>>2c)&3)<<4 | ((b3>>2c)&3)<<6
// where b_k = ballot(state of node 4*lane+k).  Per-chunk max sum ~12.9K
// (uint16 safe; 4-chunk group sums <= 51808: packed-u16 adds can't overflow).
__global__ void build_T2(const uint8_t* __restrict__ wres, const int* __restrict__ primes,
                         const int* __restrict__ flag, uint16_t* __restrict__ T2) {
    const int v = blockIdx.x;          // 0..255 permuted byte value
    const int c = blockIdx.y;          // 0..31 chunk
    const int j = threadIdx.x;         // 0..255 node
    const int stride = (*flag) ? 1 : 4;
    int sum = 0;
#pragma unroll
    for (int p = 0; p < 8; ++p) {
        if ((v >> p) & 1) {
            const int k = c * 8 + ((p & 1) << 2) + (p >> 1);
            if (wres[(size_t)(j * 256 + k) * stride]) sum += primes[k];
        }
    }
    T2[((size_t)v * 32 + c) * 256 + j] = (uint16_t)sum;
}

// ---------------- bit-pack the LUT: 256MB int32 -> 8MB bits ----------------
__device__ __forceinline__ uint32_t spread8(uint32_t x) {
    // bit i of low byte -> bit 4*i
    x = (x | (x << 12)) & 0x000F000Fu;
    x = (x | (x << 6))  & 0x03030303u;
    x = (x | (x << 3))  & 0x11111111u;
    return x;
}
__global__ void pack_lut(const int* __restrict__ lut, uint32_t* __restrict__ lp32) {
    const int lane = threadIdx.x & 63;
    const int gw = blockIdx.x * (blockDim.x >> 6) + (threadIdx.x >> 6); // 16384 waves
    const int4* src = (const int4*)lut;
    for (int it = 0; it < 16; ++it) {
        const int chunk = gw * 16 + it;                // 262144 wave-chunks total
        const int4 q = src[(size_t)chunk * 64 + lane]; // coalesced 16B/lane
        const uint64_t b0 = __ballot((q.x & 1) != 0);
        const uint64_t b1 = __ballot((q.y & 1) != 0);
        const uint64_t b2 = __ballot((q.z & 1) != 0);
        const uint64_t b3 = __ballot((q.w & 1) != 0);
        if (lane < 8) {
            const uint32_t B0 = (uint32_t)(b0 >> (8 * lane)) & 0xFF;
            const uint32_t B1 = (uint32_t)(b1 >> (8 * lane)) & 0xFF;
            const uint32_t B2 = (uint32_t)(b2 >> (8 * lane)) & 0xFF;
            const uint32_t B3 = (uint32_t)(b3 >> (8 * lane)) & 0xFF;
            const uint32_t w = spread8(B0) | (spread8(B1) << 1)
                             | (spread8(B2) << 2) | (spread8(B3) << 3);
            lp32[(size_t)chunk * 8 + lane] = w;
        }
    }
}

// ---------------- main reservoir scan: ONE WAVE per sample ----------------
// 512 blocks x 64 threads; lane l owns nodes 4l..4l+3.  No barriers/LDS in
// the serial loop.  KEY FIX vs previous round: the 32 T2 row-gathers are
// loaded into an explicit fully-unrolled register array d[32] (64 VGPRs)
// BEFORE any accumulation, so all 32 loads are in flight in one memory
// round-trip.  Previous version interleaved load+add in 4-load groups and
// the compiler (at 44 VGPRs) serialized it into ~8 dependent MALL round
// trips (measured 5040 cy/step).  Target chain ~1750 cy/step.
__global__ __launch_bounds__(64, 1) void reservoir_wave(
    const uint32_t* __restrict__ xp, const uint16_t* __restrict__ T2,
    const uint64_t* __restrict__ lp, const int* __restrict__ input_nodes,
    const uint8_t* __restrict__ init_res, const int* __restrict__ flag,
    const float* __restrict__ rW, const float* __restrict__ rb,
    float* __restrict__ out)
{
    const int m = blockIdx.x;
    const int l = threadIdx.x;          // lane 0..63
    const int stride = (*flag) ? 1 : 4;

    // input-slot assignment for this lane's 4 nodes
    int slot0 = -1, slot1 = -1, slot2 = -1, slot3 = -1;
    for (int i = 0; i < 32; ++i) {
        const int n = input_nodes[i];
        if (n == 4 * l + 0) slot0 = i;
        if (n == 4 * l + 1) slot1 = i;
        if (n == 4 * l + 2) slot2 = i;
        if (n == 4 * l + 3) slot3 = i;
    }
    int v0 = init_res[(size_t)(4 * l + 0) * stride] ? 1 : 0;
    int v1 = init_res[(size_t)(4 * l + 1) * stride] ? 1 : 0;
    int v2 = init_res[(size_t)(4 * l + 2) * stride] ? 1 : 0;
    int v3 = init_res[(size_t)(4 * l + 3) * stride] ? 1 : 0;

    const uint32_t* xrow = xp + m * S_STEPS;
    const uint16_t* T2l  = T2 + 4 * l;          // column base for this lane

    for (int s = 0; s < S_STEPS; ++s) {
        const uint32_t xw = xrow[s];
        if (slot0 >= 0) v0 = (xw >> slot0) & 1;
        if (slot1 >= 0) v1 = (xw >> slot1) & 1;
        if (slot2 >= 0) v2 = (xw >> slot2) & 1;
        if (slot3 >= 0) v3 = (xw >> slot3) & 1;

        const uint64_t b0 = __ballot(v0 != 0);
        const uint64_t b1 = __ballot(v1 != 0);
        const uint64_t b2 = __ballot(v2 != 0);
        const uint64_t b3 = __ballot(v3 != 0);

        // lane c (c<32) holds the permuted byte for chunk c
        const int sh = (2 * l) & 63;
        const uint32_t u = (((uint32_t)(b0 >> sh) & 3u))
                         | (((uint32_t)(b1 >> sh) & 3u) << 2)
                         | (((uint32_t)(b2 >> sh) & 3u) << 4)
                         | (((uint32_t)(b3 >> sh) & 3u) << 6);

        // ---- phase 1: issue ALL 32 row loads (static-index reg array) ----
        uint2 d[32];
#pragma unroll
        for (int c = 0; c < 32; ++c) {
            const int uc = __builtin_amdgcn_readlane((int)u, c) & 0xFF;
            d[c] = *(const uint2*)(T2l + (size_t)(((uc << 5) + c) << 8));
        }

        // ---- phase 2: packed u16x2 reduction (fields <= 51808, no ovfl) --
        uint32_t i0 = 0, i1 = 0, i2 = 0, i3 = 0;
#pragma unroll
        for (int g = 0; g < 8; ++g) {
            const uint32_t lo = d[4 * g].x + d[4 * g + 1].x + d[4 * g + 2].x + d[4 * g + 3].x;
            const uint32_t hi = d[4 * g].y + d[4 * g + 1].y + d[4 * g + 2].y + d[4 * g + 3].y;
            i0 += lo & 0xFFFFu;  i1 += lo >> 16;
            i2 += hi & 0xFFFFu;  i3 += hi >> 16;
        }

        // ---- phase 3: 4 independent LUT-bit loads ------------------------
        const uint64_t w0 = lp[((size_t)(4 * l + 0) << 12) + (i0 >> 6)];
        const uint64_t w1 = lp[((size_t)(4 * l + 1) << 12) + (i1 >> 6)];
        const uint64_t w2 = lp[((size_t)(4 * l + 2) << 12) + (i2 >> 6)];
        const uint64_t w3 = lp[((size_t)(4 * l + 3) << 12) + (i3 >> 6)];
        v0 = (int)((w0 >> (i0 & 63)) & 1);
        v1 = (int)((w1 >> (i1 & 63)) & 1);
        v2 = (int)((w2 >> (i2 & 63)) & 1);
        v3 = (int)((w3 >> (i3 & 63)) & 1);
    }

    // readout: out[m][o] = b[o] + sum_j v_j * W[o][j]  (wave shuffle reduce)
#pragma unroll
    for (int o = 0; o < OUT_N; ++o) {
        const float* wrow = rW + o * R_NODES + 4 * l;
        float c = 0.f;
        if (v0) c += wrow[0];
        if (v1) c += wrow[1];
        if (v2) c += wrow[2];
        if (v3) c += wrow[3];
#pragma unroll
        for (int off = 32; off > 0; off >>= 1)
            c += __shfl_down(c, off, 64);
        if (l == 0) out[m * OUT_N + o] = c + rb[o];
    }
}

extern "C" void kernel_launch(void* const* d_in, const int* in_sizes, int n_in,
                              void* d_out, int out_size, void* d_ws, size_t ws_size,
                              hipStream_t stream) {
    const uint8_t* x        = (const uint8_t*)d_in[0];   // bool [M,S,D,B]
    const int* input_nodes  = (const int*)d_in[1];       // int32 [32]
    const int* lut          = (const int*)d_in[2];       // int32 [256, 2^18]
    const uint8_t* wres     = (const uint8_t*)d_in[3];   // bool [256,256]
    const int* primes       = (const int*)d_in[4];       // int32 [256]
    const uint8_t* init_res = (const uint8_t*)d_in[5];   // bool [256]
    const float* rW         = (const float*)d_in[6];     // f32 [10,256]
    const float* rb         = (const float*)d_in[7];     // f32 [10]
    float* out              = (float*)d_out;             // f32 [512,10]

    uint8_t* ws = (uint8_t*)d_ws;
    int*      flag = (int*)ws;                                        // 4 B
    uint32_t* xp   = (uint32_t*)(ws + 4096);                          // 1 MB
    uint16_t* T2   = (uint16_t*)(ws + 4096 + 1048576);                // 4 MB
    uint64_t* lp   = (uint64_t*)(ws + 4096 + 1048576 + 4194304);      // 8 MB

    detect_layout<<<1, 256, 0, stream>>>(x, flag);
    pack_x<<<(M_SAMP * S_STEPS * 32) / 256, 256, 0, stream>>>(x, flag, xp);
    build_T2<<<dim3(256, 32), 256, 0, stream>>>(wres, primes, flag, T2);
    pack_lut<<<4096, 256, 0, stream>>>(lut, (uint32_t*)lp);
    reservoir_wave<<<M_SAMP, 64, 0, stream>>>(xp, T2, lp, input_nodes, init_res,
                                              flag, rW, rb, out);
}

// Round 3
// 1224.617 us; speedup vs baseline: 1.2128x; 1.2128x over previous
//
#include <hip/hip_runtime.h>
#include <stdint.h>

#define R_NODES 256
#define M_SAMP  512
#define S_STEPS 512
#define OUT_N   10

// ---------------- layout detection for bool inputs ----------------
// If bools were uploaded as int32, byte (4f+1) of every element is 0.
// If uploaded as uint8, ~half those bytes are 1.  flag=1 => uint8 layout.
__global__ void detect_layout(const uint8_t* __restrict__ x, int* __restrict__ flag) {
    __shared__ int any;
    if (threadIdx.x == 0) any = 0;
    __syncthreads();
    int acc = 0;
    for (int i = 0; i < 64; ++i)
        acc |= x[(size_t)(threadIdx.x * 64 + i) * 4 + 1];
    if (acc) atomicOr(&any, 1);
    __syncthreads();
    if (threadIdx.x == 0) *flag = any ? 1 : 0;
}

// ---------------- pack x bits: one uint32 per (m,s) ----------------
__global__ void pack_x(const uint8_t* __restrict__ x, const int* __restrict__ flag,
                       uint32_t* __restrict__ xp) {
    const int stride = (*flag) ? 1 : 4;
    const int f = blockIdx.x * blockDim.x + threadIdx.x;      // element idx, M*S*32 total
    const int val = x[(size_t)f * stride];
    const uint64_t mask = __ballot(val != 0);
    const int lane = threadIdx.x & 63;
    if ((lane & 31) == 0) {
        uint32_t w = (lane & 32) ? (uint32_t)(mask >> 32) : (uint32_t)mask;
        xp[f >> 5] = w;
    }
}

// ---------------- build byte-chunk partial-sum table (permuted bits) ----
// T2[(v*32 + c)*256 + j]: bit p of v refers to node column
//     k = c*8 + (p&1)*4 + (p>>1)
// matching the main kernel's ballot-derived byte
//     u_c = ((b0>>2c)&3) | ((b1>>2c)&3)<<2 | ((b2>>2c)&3)<<4 | ((b3>>2c)&3)<<6
// where b_k = ballot(state of node 4*lane+k).  Per-chunk max sum ~12.9K
// (uint16 safe; 4-chunk group sums <= 51808: packed-u16 adds can't overflow).
__global__ void build_T2(const uint8_t* __restrict__ wres, const int* __restrict__ primes,
                         const int* __restrict__ flag, uint16_t* __restrict__ T2) {
    const int v = blockIdx.x;          // 0..255 permuted byte value
    const int c = blockIdx.y;          // 0..31 chunk
    const int j = threadIdx.x;         // 0..255 node
    const int stride = (*flag) ? 1 : 4;
    int sum = 0;
#pragma unroll
    for (int p = 0; p < 8; ++p) {
        if ((v >> p) & 1) {
            const int k = c * 8 + ((p & 1) << 2) + (p >> 1);
            if (wres[(size_t)(j * 256 + k) * stride]) sum += primes[k];
        }
    }
    T2[((size_t)v * 32 + c) * 256 + j] = (uint16_t)sum;
}

// ---------------- bit-pack the LUT: 256MB int32 -> 8MB bits ----------------
__device__ __forceinline__ uint32_t spread8(uint32_t x) {
    // bit i of low byte -> bit 4*i
    x = (x | (x << 12)) & 0x000F000Fu;
    x = (x | (x << 6))  & 0x03030303u;
    x = (x | (x << 3))  & 0x11111111u;
    return x;
}
__global__ void pack_lut(const int* __restrict__ lut, uint32_t* __restrict__ lp32) {
    const int lane = threadIdx.x & 63;
    const int gw = blockIdx.x * (blockDim.x >> 6) + (threadIdx.x >> 6); // 16384 waves
    const int4* src = (const int4*)lut;
    for (int it = 0; it < 16; ++it) {
        const int chunk = gw * 16 + it;                // 262144 wave-chunks total
        const int4 q = src[(size_t)chunk * 64 + lane]; // coalesced 16B/lane
        const uint64_t b0 = __ballot((q.x & 1) != 0);
        const uint64_t b1 = __ballot((q.y & 1) != 0);
        const uint64_t b2 = __ballot((q.z & 1) != 0);
        const uint64_t b3 = __ballot((q.w & 1) != 0);
        if (lane < 8) {
            const uint32_t B0 = (uint32_t)(b0 >> (8 * lane)) & 0xFF;
            const uint32_t B1 = (uint32_t)(b1 >> (8 * lane)) & 0xFF;
            const uint32_t B2 = (uint32_t)(b2 >> (8 * lane)) & 0xFF;
            const uint32_t B3 = (uint32_t)(b3 >> (8 * lane)) & 0xFF;
            const uint32_t w = spread8(B0) | (spread8(B1) << 1)
                             | (spread8(B2) << 2) | (spread8(B3) << 3);
            lp32[(size_t)chunk * 8 + lane] = w;
        }
    }
}

// ---------------- main reservoir scan: ONE WAVE per sample ----------------
// 512 blocks x 64 threads; lane l owns nodes 4l..4l+3.  No barriers/LDS in
// the serial loop.
// KEY FIX vs rounds 1-2: the machine scheduler kept sinking the 32 T2 row
// loads into the reduction (VGPR stayed 44 -> ~8 dependent memory round
// trips, 5060 cy/step).  __builtin_amdgcn_sched_barrier(0) between the
// load phase and the reduce phase forbids that motion: all 32
// global_load_dwordx2 must issue first, giving ONE latency exposure with
// progressive vmcnt waits.  Next-step xw is prefetched inside the latency
// window.  Diagnostic: VGPR_Count must rise to >=110, else the fence failed.
__global__ __launch_bounds__(64, 1) void reservoir_wave(
    const uint32_t* __restrict__ xp, const uint16_t* __restrict__ T2,
    const uint64_t* __restrict__ lp, const int* __restrict__ input_nodes,
    const uint8_t* __restrict__ init_res, const int* __restrict__ flag,
    const float* __restrict__ rW, const float* __restrict__ rb,
    float* __restrict__ out)
{
    const int m = blockIdx.x;
    const int l = threadIdx.x;          // lane 0..63
    const int stride = (*flag) ? 1 : 4;

    // input-slot assignment for this lane's 4 nodes
    int slot0 = -1, slot1 = -1, slot2 = -1, slot3 = -1;
    for (int i = 0; i < 32; ++i) {
        const int n = input_nodes[i];
        if (n == 4 * l + 0) slot0 = i;
        if (n == 4 * l + 1) slot1 = i;
        if (n == 4 * l + 2) slot2 = i;
        if (n == 4 * l + 3) slot3 = i;
    }
    int v0 = init_res[(size_t)(4 * l + 0) * stride] ? 1 : 0;
    int v1 = init_res[(size_t)(4 * l + 1) * stride] ? 1 : 0;
    int v2 = init_res[(size_t)(4 * l + 2) * stride] ? 1 : 0;
    int v3 = init_res[(size_t)(4 * l + 3) * stride] ? 1 : 0;

    const uint32_t* xrow = xp + m * S_STEPS;
    const uint16_t* T2l  = T2 + 4 * l;          // column base for this lane

    uint32_t xw = xrow[0];
    for (int s = 0; s < S_STEPS; ++s) {
        if (slot0 >= 0) v0 = (xw >> slot0) & 1;
        if (slot1 >= 0) v1 = (xw >> slot1) & 1;
        if (slot2 >= 0) v2 = (xw >> slot2) & 1;
        if (slot3 >= 0) v3 = (xw >> slot3) & 1;

        const uint64_t b0 = __ballot(v0 != 0);
        const uint64_t b1 = __ballot(v1 != 0);
        const uint64_t b2 = __ballot(v2 != 0);
        const uint64_t b3 = __ballot(v3 != 0);

        // lane c (c<32) holds the permuted byte for chunk c
        const int sh = (2 * l) & 63;
        const uint32_t u = (((uint32_t)(b0 >> sh) & 3u))
                         | (((uint32_t)(b1 >> sh) & 3u) << 2)
                         | (((uint32_t)(b2 >> sh) & 3u) << 4)
                         | (((uint32_t)(b3 >> sh) & 3u) << 6);

        // ---- phase 1: issue ALL 32 row loads (static-index reg array) ----
        uint2 d[32];
#pragma unroll
        for (int c = 0; c < 32; ++c) {
            const int uc = __builtin_amdgcn_readlane((int)u, c) & 0xFF;
            d[c] = *(const uint2*)(T2l + (size_t)(((uc << 5) + c) << 8));
        }
        // prefetch next step's input word inside the T2 latency window
        const uint32_t xw_next = xrow[(s + 1 < S_STEPS) ? s + 1 : s];

        // scheduling fence: loads above may NOT sink past this point,
        // adds below may not hoist above it -> one memory round-trip.
        __builtin_amdgcn_sched_barrier(0);

        // ---- phase 2: packed u16x2 reduction (fields <= 51808, no ovfl) --
        uint32_t i0 = 0, i1 = 0, i2 = 0, i3 = 0;
#pragma unroll
        for (int g = 0; g < 8; ++g) {
            const uint32_t lo = d[4 * g].x + d[4 * g + 1].x + d[4 * g + 2].x + d[4 * g + 3].x;
            const uint32_t hi = d[4 * g].y + d[4 * g + 1].y + d[4 * g + 2].y + d[4 * g + 3].y;
            i0 += lo & 0xFFFFu;  i1 += lo >> 16;
            i2 += hi & 0xFFFFu;  i3 += hi >> 16;
        }

        // ---- phase 3: 4 independent LUT-bit loads ------------------------
        const uint64_t w0 = lp[((size_t)(4 * l + 0) << 12) + (i0 >> 6)];
        const uint64_t w1 = lp[((size_t)(4 * l + 1) << 12) + (i1 >> 6)];
        const uint64_t w2 = lp[((size_t)(4 * l + 2) << 12) + (i2 >> 6)];
        const uint64_t w3 = lp[((size_t)(4 * l + 3) << 12) + (i3 >> 6)];
        __builtin_amdgcn_sched_barrier(0);
        v0 = (int)((w0 >> (i0 & 63)) & 1);
        v1 = (int)((w1 >> (i1 & 63)) & 1);
        v2 = (int)((w2 >> (i2 & 63)) & 1);
        v3 = (int)((w3 >> (i3 & 63)) & 1);
        xw = xw_next;
    }

    // readout: out[m][o] = b[o] + sum_j v_j * W[o][j]  (wave shuffle reduce)
#pragma unroll
    for (int o = 0; o < OUT_N; ++o) {
        const float* wrow = rW + o * R_NODES + 4 * l;
        float c = 0.f;
        if (v0) c += wrow[0];
        if (v1) c += wrow[1];
        if (v2) c += wrow[2];
        if (v3) c += wrow[3];
#pragma unroll
        for (int off = 32; off > 0; off >>= 1)
            c += __shfl_down(c, off, 64);
        if (l == 0) out[m * OUT_N + o] = c + rb[o];
    }
}

extern "C" void kernel_launch(void* const* d_in, const int* in_sizes, int n_in,
                              void* d_out, int out_size, void* d_ws, size_t ws_size,
                              hipStream_t stream) {
    const uint8_t* x        = (const uint8_t*)d_in[0];   // bool [M,S,D,B]
    const int* input_nodes  = (const int*)d_in[1];       // int32 [32]
    const int* lut          = (const int*)d_in[2];       // int32 [256, 2^18]
    const uint8_t* wres     = (const uint8_t*)d_in[3];   // bool [256,256]
    const int* primes       = (const int*)d_in[4];       // int32 [256]
    const uint8_t* init_res = (const uint8_t*)d_in[5];   // bool [256]
    const float* rW         = (const float*)d_in[6];     // f32 [10,256]
    const float* rb         = (const float*)d_in[7];     // f32 [10]
    float* out              = (float*)d_out;             // f32 [512,10]

    uint8_t* ws = (uint8_t*)d_ws;
    int*      flag = (int*)ws;                                        // 4 B
    uint32_t* xp   = (uint32_t*)(ws + 4096);                          // 1 MB
    uint16_t* T2   = (uint16_t*)(ws + 4096 + 1048576);                // 4 MB
    uint64_t* lp   = (uint64_t*)(ws + 4096 + 1048576 + 4194304);      // 8 MB

    detect_layout<<<1, 256, 0, stream>>>(x, flag);
    pack_x<<<(M_SAMP * S_STEPS * 32) / 256, 256, 0, stream>>>(x, flag, xp);
    build_T2<<<dim3(256, 32), 256, 0, stream>>>(wres, primes, flag, T2);
    pack_lut<<<4096, 256, 0, stream>>>(lut, (uint32_t*)lp);
    reservoir_wave<<<M_SAMP, 64, 0, stream>>>(xp, T2, lp, input_nodes, init_res,
                                              flag, rW, rb, out);
}

// Round 4
// 1099.141 us; speedup vs baseline: 1.3512x; 1.1142x over previous
//
#include <hip/hip_runtime.h>
#include <stdint.h>

#define R_NODES 256
#define M_SAMP  512
#define S_STEPS 512
#define OUT_N   10

typedef unsigned int u32x2 __attribute__((ext_vector_type(2)));

// ---------------- layout detection for bool inputs ----------------
// If bools were uploaded as int32, byte (4f+1) of every element is 0.
// If uploaded as uint8, ~half those bytes are 1.  flag=1 => uint8 layout.
__global__ void detect_layout(const uint8_t* __restrict__ x, int* __restrict__ flag) {
    __shared__ int any;
    if (threadIdx.x == 0) any = 0;
    __syncthreads();
    int acc = 0;
    for (int i = 0; i < 64; ++i)
        acc |= x[(size_t)(threadIdx.x * 64 + i) * 4 + 1];
    if (acc) atomicOr(&any, 1);
    __syncthreads();
    if (threadIdx.x == 0) *flag = any ? 1 : 0;
}

// ---------------- pack x bits: one uint32 per (m,s) ----------------
__global__ void pack_x(const uint8_t* __restrict__ x, const int* __restrict__ flag,
                       uint32_t* __restrict__ xp) {
    const int stride = (*flag) ? 1 : 4;
    const int f = blockIdx.x * blockDim.x + threadIdx.x;      // element idx, M*S*32 total
    const int val = x[(size_t)f * stride];
    const uint64_t mask = __ballot(val != 0);
    const int lane = threadIdx.x & 63;
    if ((lane & 31) == 0) {
        uint32_t w = (lane & 32) ? (uint32_t)(mask >> 32) : (uint32_t)mask;
        xp[f >> 5] = w;
    }
}

// ---------------- build byte-chunk partial-sum table (permuted bits) ----
// T2[(v*32 + c)*256 + j]: bit p of v refers to node column
//     k = c*8 + (p&1)*4 + (p>>1)
// matching the main kernel's ballot-derived byte
//     u_c = ((b0>>2c)&3) | ((b1>>2c)&3)<<2 | ((b2>>2c)&3)<<4 | ((b3>>2c)&3)<<6
// where b_k = ballot(state of node 4*lane+k).  Per-chunk max sum ~12.9K
// (uint16 safe; 4-chunk group sums <= 51808: packed-u16 adds can't overflow).
__global__ void build_T2(const uint8_t* __restrict__ wres, const int* __restrict__ primes,
                         const int* __restrict__ flag, uint16_t* __restrict__ T2) {
    const int v = blockIdx.x;          // 0..255 permuted byte value
    const int c = blockIdx.y;          // 0..31 chunk
    const int j = threadIdx.x;         // 0..255 node
    const int stride = (*flag) ? 1 : 4;
    int sum = 0;
#pragma unroll
    for (int p = 0; p < 8; ++p) {
        if ((v >> p) & 1) {
            const int k = c * 8 + ((p & 1) << 2) + (p >> 1);
            if (wres[(size_t)(j * 256 + k) * stride]) sum += primes[k];
        }
    }
    T2[((size_t)v * 32 + c) * 256 + j] = (uint16_t)sum;
}

// ---------------- bit-pack the LUT: 256MB int32 -> 8MB bits ----------------
__device__ __forceinline__ uint32_t spread8(uint32_t x) {
    // bit i of low byte -> bit 4*i
    x = (x | (x << 12)) & 0x000F000Fu;
    x = (x | (x << 6))  & 0x03030303u;
    x = (x | (x << 3))  & 0x11111111u;
    return x;
}
__global__ void pack_lut(const int* __restrict__ lut, uint32_t* __restrict__ lp32) {
    const int lane = threadIdx.x & 63;
    const int gw = blockIdx.x * (blockDim.x >> 6) + (threadIdx.x >> 6); // 16384 waves
    const int4* src = (const int4*)lut;
    for (int it = 0; it < 16; ++it) {
        const int chunk = gw * 16 + it;                // 262144 wave-chunks total
        const int4 q = src[(size_t)chunk * 64 + lane]; // coalesced 16B/lane
        const uint64_t b0 = __ballot((q.x & 1) != 0);
        const uint64_t b1 = __ballot((q.y & 1) != 0);
        const uint64_t b2 = __ballot((q.z & 1) != 0);
        const uint64_t b3 = __ballot((q.w & 1) != 0);
        if (lane < 8) {
            const uint32_t B0 = (uint32_t)(b0 >> (8 * lane)) & 0xFF;
            const uint32_t B1 = (uint32_t)(b1 >> (8 * lane)) & 0xFF;
            const uint32_t B2 = (uint32_t)(b2 >> (8 * lane)) & 0xFF;
            const uint32_t B3 = (uint32_t)(b3 >> (8 * lane)) & 0xFF;
            const uint32_t w = spread8(B0) | (spread8(B1) << 1)
                             | (spread8(B2) << 2) | (spread8(B3) << 3);
            lp32[(size_t)chunk * 8 + lane] = w;
        }
    }
}

// ---------------- main reservoir scan: ONE WAVE per sample ----------------
// 512 blocks x 64 threads; lane l owns nodes 4l..4l+3.  No barriers/LDS in
// the serial loop.
// KEY FIX vs rounds 1-3: rounds 1-2 (pure C) and round 3 (sched_barrier)
// all failed to keep the 32 T2 gathers in flight together (VGPR stayed 44
// -> multiple dependent round-trips).  Now the loads are INLINE ASM:
//   - lane c computes its row's byte offset (uc<<14)|(c<<9) in VALU,
//     one v_readlane per chunk moves it to an SGPR, +base -> saddr
//   - 32 x asm volatile global_load_dwordx2 (volatile => totally ordered,
//     nothing can interleave or sink them; 32 distinct "=v" outputs force
//     64 live VGPRs)
//   - one s_waitcnt vmcnt(0), then "+v" launder asm so no consumer can be
//     hoisted above the wait (asm outputs carry no waitcnt dep otherwise)
// Manual vmcnt is safe vs compiler-issued loads: its own waits can only
// over-wait with extra ops in flight, never under-wait.
__global__ __launch_bounds__(64, 1) void reservoir_wave(
    const uint32_t* __restrict__ xp, const uint16_t* __restrict__ T2,
    const uint64_t* __restrict__ lp, const int* __restrict__ input_nodes,
    const uint8_t* __restrict__ init_res, const int* __restrict__ flag,
    const float* __restrict__ rW, const float* __restrict__ rb,
    float* __restrict__ out)
{
    const int m = blockIdx.x;
    const int l = threadIdx.x;          // lane 0..63
    const int stride = (*flag) ? 1 : 4;

    // input-slot assignment for this lane's 4 nodes
    int slot0 = -1, slot1 = -1, slot2 = -1, slot3 = -1;
    for (int i = 0; i < 32; ++i) {
        const int n = input_nodes[i];
        if (n == 4 * l + 0) slot0 = i;
        if (n == 4 * l + 1) slot1 = i;
        if (n == 4 * l + 2) slot2 = i;
        if (n == 4 * l + 3) slot3 = i;
    }
    int v0 = init_res[(size_t)(4 * l + 0) * stride] ? 1 : 0;
    int v1 = init_res[(size_t)(4 * l + 1) * stride] ? 1 : 0;
    int v2 = init_res[(size_t)(4 * l + 2) * stride] ? 1 : 0;
    int v3 = init_res[(size_t)(4 * l + 3) * stride] ? 1 : 0;

    const uint32_t* xrow = xp + m * S_STEPS;
    const uint64_t t2base = (uint64_t)(uintptr_t)T2;
    const uint32_t voff = (uint32_t)(l << 3);     // 8*l: this lane's 4 u16 cols

    uint32_t xw = xrow[0];
    for (int s = 0; s < S_STEPS; ++s) {
        if (slot0 >= 0) v0 = (xw >> slot0) & 1;
        if (slot1 >= 0) v1 = (xw >> slot1) & 1;
        if (slot2 >= 0) v2 = (xw >> slot2) & 1;
        if (slot3 >= 0) v3 = (xw >> slot3) & 1;

        const uint64_t b0 = __ballot(v0 != 0);
        const uint64_t b1 = __ballot(v1 != 0);
        const uint64_t b2 = __ballot(v2 != 0);
        const uint64_t b3 = __ballot(v3 != 0);

        // lane c (c<32) holds the permuted byte for chunk c
        const int sh = (2 * l) & 63;
        const uint32_t u = (((uint32_t)(b0 >> sh) & 3u))
                         | (((uint32_t)(b1 >> sh) & 3u) << 2)
                         | (((uint32_t)(b2 >> sh) & 3u) << 4)
                         | (((uint32_t)(b3 >> sh) & 3u) << 6);
        // lane c's T2 row byte-offset: row=(uc*32+c), off=row*512
        const uint32_t vtmp = ((u & 0xFFu) << 14) | ((uint32_t)l << 9);

        // ---- phase 1: 32 batched row loads (inline asm, one round-trip) --
        u32x2 d[32];
#pragma unroll
        for (int c = 0; c < 32; ++c) {
            const uint32_t so = (uint32_t)__builtin_amdgcn_readlane((int)vtmp, c);
            const uint64_t sa = t2base + so;
            asm volatile("global_load_dwordx2 %0, %1, %2"
                         : "=v"(d[c]) : "v"(voff), "s"(sa));
        }
        // prefetch next step's input word inside the latency window
        const uint32_t xw_next = xrow[(s + 1 < S_STEPS) ? s + 1 : s];

        asm volatile("s_waitcnt vmcnt(0)");
        // launder: consumers of d[] must stay after the waitcnt
#pragma unroll
        for (int c = 0; c < 32; c += 8)
            asm volatile("" : "+v"(d[c]), "+v"(d[c+1]), "+v"(d[c+2]), "+v"(d[c+3]),
                              "+v"(d[c+4]), "+v"(d[c+5]), "+v"(d[c+6]), "+v"(d[c+7]));

        // ---- phase 2: packed u16x2 reduction (fields <= 51808, no ovfl) --
        uint32_t i0 = 0, i1 = 0, i2 = 0, i3 = 0;
#pragma unroll
        for (int g = 0; g < 8; ++g) {
            const uint32_t lo = d[4*g][0] + d[4*g+1][0] + d[4*g+2][0] + d[4*g+3][0];
            const uint32_t hi = d[4*g][1] + d[4*g+1][1] + d[4*g+2][1] + d[4*g+3][1];
            i0 += lo & 0xFFFFu;  i1 += lo >> 16;
            i2 += hi & 0xFFFFu;  i3 += hi >> 16;
        }

        // ---- phase 3: 4 independent LUT-bit loads ------------------------
        const uint64_t w0 = lp[((size_t)(4 * l + 0) << 12) + (i0 >> 6)];
        const uint64_t w1 = lp[((size_t)(4 * l + 1) << 12) + (i1 >> 6)];
        const uint64_t w2 = lp[((size_t)(4 * l + 2) << 12) + (i2 >> 6)];
        const uint64_t w3 = lp[((size_t)(4 * l + 3) << 12) + (i3 >> 6)];
        v0 = (int)((w0 >> (i0 & 63)) & 1);
        v1 = (int)((w1 >> (i1 & 63)) & 1);
        v2 = (int)((w2 >> (i2 & 63)) & 1);
        v3 = (int)((w3 >> (i3 & 63)) & 1);
        xw = xw_next;
    }

    // readout: out[m][o] = b[o] + sum_j v_j * W[o][j]  (wave shuffle reduce)
#pragma unroll
    for (int o = 0; o < OUT_N; ++o) {
        const float* wrow = rW + o * R_NODES + 4 * l;
        float c = 0.f;
        if (v0) c += wrow[0];
        if (v1) c += wrow[1];
        if (v2) c += wrow[2];
        if (v3) c += wrow[3];
#pragma unroll
        for (int off = 32; off > 0; off >>= 1)
            c += __shfl_down(c, off, 64);
        if (l == 0) out[m * OUT_N + o] = c + rb[o];
    }
}

extern "C" void kernel_launch(void* const* d_in, const int* in_sizes, int n_in,
                              void* d_out, int out_size, void* d_ws, size_t ws_size,
                              hipStream_t stream) {
    const uint8_t* x        = (const uint8_t*)d_in[0];   // bool [M,S,D,B]
    const int* input_nodes  = (const int*)d_in[1];       // int32 [32]
    const int* lut          = (const int*)d_in[2];       // int32 [256, 2^18]
    const uint8_t* wres     = (const uint8_t*)d_in[3];   // bool [256,256]
    const int* primes       = (const int*)d_in[4];       // int32 [256]
    const uint8_t* init_res = (const uint8_t*)d_in[5];   // bool [256]
    const float* rW         = (const float*)d_in[6];     // f32 [10,256]
    const float* rb         = (const float*)d_in[7];     // f32 [10]
    float* out              = (float*)d_out;             // f32 [512,10]

    uint8_t* ws = (uint8_t*)d_ws;
    int*      flag = (int*)ws;                                        // 4 B
    uint32_t* xp   = (uint32_t*)(ws + 4096);                          // 1 MB
    uint16_t* T2   = (uint16_t*)(ws + 4096 + 1048576);                // 4 MB
    uint64_t* lp   = (uint64_t*)(ws + 4096 + 1048576 + 4194304);      // 8 MB

    detect_layout<<<1, 256, 0, stream>>>(x, flag);
    pack_x<<<(M_SAMP * S_STEPS * 32) / 256, 256, 0, stream>>>(x, flag, xp);
    build_T2<<<dim3(256, 32), 256, 0, stream>>>(wres, primes, flag, T2);
    pack_lut<<<4096, 256, 0, stream>>>(lut, (uint32_t*)lp);
    reservoir_wave<<<M_SAMP, 64, 0, stream>>>(xp, T2, lp, input_nodes, init_res,
                                              flag, rW, rb, out);
}